// Round 5
// baseline (1973.208 us; speedup 1.0000x reference)
//
#include <hip/hip_runtime.h>

// GCN 4-layer: 29->96->128->64->32, N=50000, E=800000 (+self loops).
// Round 5: wave-uniform-W GEMM. lane = node => W[k][n] is wave-uniform
// (compiler scalarizes to s_load, SGPR operand in v_fma); X row segment in
// VGPRs; 32 cols per wave; epilogue transposed through per-wave LDS tile
// (swizzled, conflict-free) for coalesced float4 stores.
// ELL pull-aggregation unchanged from round 4 (CAP=64, transposed layout).
// NOTE: harness delivers integer inputs as int32.

constexpr int NN  = 50000;
constexpr int CAP = 64;   // max in-degree; Poisson(16) over 50K nodes => P(>=64) ~ 0

// Fused degree-count + ELL placement. cnt must be zeroed first.
__global__ void place_ell_kernel(const int* __restrict__ row, const int* __restrict__ col,
                                 int* __restrict__ cnt, int* __restrict__ ell, int E) {
    int e = blockIdx.x * blockDim.x + threadIdx.x;
    if (e < E) {
        int c = col[e], r = row[e];
        if ((unsigned)c < (unsigned)NN && (unsigned)r < (unsigned)NN) {
            int pos = atomicAdd(&cnt[c], 1);
            if (pos < CAP) ell[pos * NN + c] = r;   // guard keeps rocprof replays safe
        }
    }
}

__global__ void dis_kernel(const int* __restrict__ cnt, float* __restrict__ dis, int n) {
    int i = blockIdx.x * blockDim.x + threadIdx.x;
    if (i < n) dis[i] = rsqrtf((float)cnt[i] + 1.0f);  // +1 = self loop
}

// x (N x 29) -> xp (N x 32), pre-scaled by dis[n], cols 29..31 = 0.
__global__ void xpad_kernel(const float* __restrict__ x, const float* __restrict__ dis,
                            float* __restrict__ xp) {
    int idx = blockIdx.x * blockDim.x + threadIdx.x;
    if (idx < NN * 32) {
        int n = idx >> 5, f = idx & 31;
        xp[idx] = (f < 29) ? x[n * 29 + f] * dis[n] : 0.f;
    }
}

// Pull aggregation over ELL. One thread per (node, float4 chunk).
template<int F, bool BIAS>
__global__ void aggregate_kernel(const float* __restrict__ hs,
                                 const int* __restrict__ cnt,
                                 const int* __restrict__ ell,
                                 const float* __restrict__ dis,
                                 const float* __restrict__ bias,
                                 float* __restrict__ out) {
    constexpr int CH = F / 4;
    const int idx = blockIdx.x * blockDim.x + threadIdx.x;
    if (idx >= NN * CH) return;
    const int n = idx / CH;
    const int c = idx - n * CH;
    const float4* hp = (const float4*)hs;
    float4 acc = hp[(size_t)n * CH + c];          // self-loop term
    int m = cnt[n]; if (m > CAP) m = CAP;
    for (int k = 0; k < m; ++k) {
        const int s = ell[k * NN + n];
        const float4 v = hp[(size_t)s * CH + c];
        acc.x += v.x; acc.y += v.y; acc.z += v.z; acc.w += v.w;
    }
    const float d = dis[n];
    float4 r;
    if (BIAS) {
        const float4 b4 = ((const float4*)bias)[c];
        r.x = fmaf(acc.x, d, b4.x); r.y = fmaf(acc.y, d, b4.y);
        r.z = fmaf(acc.z, d, b4.z); r.w = fmaf(acc.w, d, b4.w);
    } else {
        r.x = acc.x * d; r.y = acc.y * d; r.z = acc.z * d; r.w = acc.w * d;
    }
    ((float4*)out)[idx] = r;
}

// Wave-uniform-W GEMM. Block = (FOUT/32) waves over the SAME 64 nodes;
// wave w computes cols [32w, 32w+32). lane = node => W loads scalarize.
// MODE: 0 = acc + b ; 1 = acc * dis ; 2 = relu(acc + b) * dis
template<int K, int STRIDE, int FOUT, int MODE>
__global__ void gemm_wave_kernel(const float* __restrict__ X, const float* __restrict__ W,
                                 const float* __restrict__ bias, const float* __restrict__ dis,
                                 float* __restrict__ out) {
    constexpr int NW = FOUT / 32;
    constexpr bool FULL = (K % 32 == 0);
    __shared__ float tb[NW * 64 * 32];
    const int lane = threadIdx.x & 63;
    const int wv   = threadIdx.x >> 6;
    const int n0   = wv * 32;
    const int nodeBase = blockIdx.x * 64;
    const int node = nodeBase + lane;
    const bool valid = node < NN;

    float acc[32];
#pragma unroll
    for (int n = 0; n < 32; ++n) acc[n] = 0.f;

    const float4* xrow = (const float4*)(X + (size_t)(valid ? node : 0) * STRIDE);
    constexpr int NKT = (K + 31) / 32;
#pragma unroll
    for (int kt = 0; kt < NKT; ++kt) {
        float4 xr[8];
#pragma unroll
        for (int q = 0; q < 8; ++q) {
            if (FULL || kt * 32 + q * 4 < K) xr[q] = xrow[kt * 8 + q];
        }
#pragma unroll
        for (int q = 0; q < 8; ++q) {
#pragma unroll
            for (int j = 0; j < 4; ++j) {
                if (FULL || kt * 32 + q * 4 + j < K) {
                    const int k = kt * 32 + q * 4 + j;
                    const float xv = (j == 0) ? xr[q].x : (j == 1) ? xr[q].y
                                   : (j == 2) ? xr[q].z : xr[q].w;
                    const float* wr = W + (size_t)k * FOUT + n0;   // wave-uniform
#pragma unroll
                    for (int n = 0; n < 32; ++n) acc[n] = fmaf(xv, wr[n], acc[n]);
                }
            }
        }
    }

    // Epilogue -> per-wave LDS tile (swizzle (c+lane)&31: writes conflict-free,
    // reads <=2-way which is free), then coalesced float4 stores.
    float* tw = tb + wv * 2048;
    const float d = (MODE != 0 && valid) ? dis[node] : 0.f;
#pragma unroll
    for (int n = 0; n < 32; ++n) {
        float v = acc[n];
        if (MODE == 0)      v += bias[n0 + n];
        else if (MODE == 2) v = fmaxf(v + bias[n0 + n], 0.f) * d;
        else                v *= d;
        tw[lane * 32 + ((n + lane) & 31)] = v;
    }
    // same-wave ds_write -> ds_read: in-order per wave, lgkmcnt handled by compiler
    const int i = lane >> 3, c4 = lane & 7;
#pragma unroll
    for (int p = 0; p < 8; ++p) {
        const int r  = p * 8 + i;
        const int nr = nodeBase + r;
        if (nr < NN) {
            float4 v;
            v.x = tw[r * 32 + ((c4 * 4 + 0 + r) & 31)];
            v.y = tw[r * 32 + ((c4 * 4 + 1 + r) & 31)];
            v.z = tw[r * 32 + ((c4 * 4 + 2 + r) & 31)];
            v.w = tw[r * 32 + ((c4 * 4 + 3 + r) & 31)];
            *(float4*)(out + (size_t)nr * FOUT + n0 + c4 * 4) = v;
        }
    }
}

extern "C" void kernel_launch(void* const* d_in, const int* in_sizes, int n_in,
                              void* d_out, int out_size, void* d_ws, size_t ws_size,
                              hipStream_t stream) {
    const float* x  = (const float*)d_in[0];
    const int*   ei = (const int*)d_in[1];           // int32 (harness converts)
    const float* W1 = (const float*)d_in[2]; const float* b1 = (const float*)d_in[3];
    const float* W2 = (const float*)d_in[4]; const float* b2 = (const float*)d_in[5];
    const float* W3 = (const float*)d_in[6]; const float* b3 = (const float*)d_in[7];
    const float* W4 = (const float*)d_in[8]; const float* b4 = (const float*)d_in[9];
    float* out = (float*)d_out;

    const int E = in_sizes[1] / 2;          // 800000
    const int* row = ei;
    const int* col = ei + E;

    // Workspace (4B elems): cnt i32[50048] | dis f32[50048] | ell i32[CAP*NN]
    //                      | B0 f32[N*128] | B1 f32[N*128]    (~64.4 MB)
    int*   cnt = (int*)d_ws;
    float* dis = (float*)(cnt + 50048);
    int*   ell = (int*)(dis + 50048);
    float* B0  = (float*)(ell + (size_t)CAP * NN);
    float* B1  = B0 + (size_t)NN * 128;

    const int GB = (NN + 63) / 64;          // 782 node-blocks for gemms

    // --- build ELL + dis ---
    hipMemsetAsync(cnt, 0, 50048 * sizeof(int), stream);
    place_ell_kernel<<<(E + 255) / 256, 256, 0, stream>>>(row, col, cnt, ell, E);
    dis_kernel<<<(NN + 255) / 256, 256, 0, stream>>>(cnt, dis, NN);
    xpad_kernel<<<(NN * 32 + 255) / 256, 256, 0, stream>>>(x, dis, B0);

    // --- layer 1 (agg-first): agg32(B0->B1); gemm 29->96 relu(+b)*dis (B1->B0)
    aggregate_kernel<32, false><<<(NN * 8 + 255) / 256, 256, 0, stream>>>(B0, cnt, ell, dis, nullptr, B1);
    gemm_wave_kernel<29, 32, 96, 2><<<GB, 192, 0, stream>>>(B1, W1, b1, dis, B0);

    // --- layer 2 (agg-first): agg96(B0->B1); gemm 96->128 +b (B1->B0)
    aggregate_kernel<96, false><<<(NN * 24 + 255) / 256, 256, 0, stream>>>(B0, cnt, ell, dis, nullptr, B1);
    gemm_wave_kernel<96, 96, 128, 0><<<GB, 256, 0, stream>>>(B1, W2, b2, dis, B0);

    // --- layer 3 (gemm-first): gemm 128->64 *dis (B0->B1); agg64 +b3 (B1->B0)
    gemm_wave_kernel<128, 128, 64, 1><<<GB, 128, 0, stream>>>(B0, W3, nullptr, dis, B1);
    aggregate_kernel<64, true><<<(NN * 16 + 255) / 256, 256, 0, stream>>>(B1, cnt, ell, dis, b3, B0);

    // --- layer 4 (gemm-first): gemm 64->32 *dis (B0->B1); agg32 +b4 (B1->out)
    gemm_wave_kernel<64, 64, 32, 1><<<GB, 64, 0, stream>>>(B0, W4, nullptr, dis, B1);
    aggregate_kernel<32, true><<<(NN * 8 + 255) / 256, 256, 0, stream>>>(B1, cnt, ell, dis, b4, out);
}

// Round 6
// 366.979 us; speedup vs baseline: 5.3769x; 5.3769x over previous
//
#include <hip/hip_runtime.h>

// GCN 4-layer: 29->96->128->64->32, N=50000, E=800000 (+self loops).
// Round 6: revert to round-4 structure (426 us) + register-blocked GEMM:
// thread = (4 cols x 2 nodes), acc[8] in VGPRs, coalesced float4 W loads
// (L1-reused across node groups), LDS X rows padded +4 words (bank spread).
// Round-5 wave-GEMM spilled acc[32] to scratch (VGPR=64, 2.5 GB HBM) - dead.
// ELL pull-aggregation unchanged (CAP=64, transposed layout).
// NOTE: harness delivers integer inputs as int32.

constexpr int NN  = 50000;
constexpr int CAP = 64;   // max in-degree; Poisson(16) over 50K nodes => P(>=64) ~ 0

// Fused degree-count + ELL placement. cnt must be zeroed first.
__global__ void place_ell_kernel(const int* __restrict__ row, const int* __restrict__ col,
                                 int* __restrict__ cnt, int* __restrict__ ell, int E) {
    int e = blockIdx.x * blockDim.x + threadIdx.x;
    if (e < E) {
        int c = col[e], r = row[e];
        if ((unsigned)c < (unsigned)NN && (unsigned)r < (unsigned)NN) {
            int pos = atomicAdd(&cnt[c], 1);
            if (pos < CAP) ell[pos * NN + c] = r;   // guard keeps rocprof replays safe
        }
    }
}

__global__ void dis_kernel(const int* __restrict__ cnt, float* __restrict__ dis, int n) {
    int i = blockIdx.x * blockDim.x + threadIdx.x;
    if (i < n) dis[i] = rsqrtf((float)cnt[i] + 1.0f);  // +1 = self loop
}

// x (N x 29) -> xp (N x 32), pre-scaled by dis[n], cols 29..31 = 0.
__global__ void xpad_kernel(const float* __restrict__ x, const float* __restrict__ dis,
                            float* __restrict__ xp) {
    int idx = blockIdx.x * blockDim.x + threadIdx.x;
    if (idx < NN * 32) {
        int n = idx >> 5, f = idx & 31;
        xp[idx] = (f < 29) ? x[n * 29 + f] * dis[n] : 0.f;
    }
}

// Pull aggregation over ELL. One thread per (node, float4 chunk).
template<int F, bool BIAS>
__global__ void aggregate_kernel(const float* __restrict__ hs,
                                 const int* __restrict__ cnt,
                                 const int* __restrict__ ell,
                                 const float* __restrict__ dis,
                                 const float* __restrict__ bias,
                                 float* __restrict__ out) {
    constexpr int CH = F / 4;
    const int idx = blockIdx.x * blockDim.x + threadIdx.x;
    if (idx >= NN * CH) return;
    const int n = idx / CH;
    const int c = idx - n * CH;
    const float4* hp = (const float4*)hs;
    float4 acc = hp[(size_t)n * CH + c];          // self-loop term
    int m = cnt[n]; if (m > CAP) m = CAP;
    for (int k = 0; k < m; ++k) {
        const int s = ell[k * NN + n];
        const float4 v = hp[(size_t)s * CH + c];
        acc.x += v.x; acc.y += v.y; acc.z += v.z; acc.w += v.w;
    }
    const float d = dis[n];
    float4 r;
    if (BIAS) {
        const float4 b4 = ((const float4*)bias)[c];
        r.x = fmaf(acc.x, d, b4.x); r.y = fmaf(acc.y, d, b4.y);
        r.z = fmaf(acc.z, d, b4.z); r.w = fmaf(acc.w, d, b4.w);
    } else {
        r.x = acc.x * d; r.y = acc.y * d; r.z = acc.z * d; r.w = acc.w * d;
    }
    ((float4*)out)[idx] = r;
}

// Register-blocked GEMM: thread = (col-group cg of 4 cols, node-pair g).
// Block = (FOUT/4)*G threads, 2*G nodes. Per k: 2 LDS broadcasts + 1 float4
// W load (coalesced over cg; L1-reused over g) + 8 FMAs. acc[8] VGPRs.
// MODE: 0 = acc + b ; 1 = acc * dis ; 2 = relu(acc + b) * dis
template<int K, int STRIDE, int FOUT, int G, int MODE>
__global__ void gemm_rb_kernel(const float* __restrict__ X, const float* __restrict__ W,
                               const float* __restrict__ bias, const float* __restrict__ dis,
                               float* __restrict__ out) {
    constexpr int CG  = FOUT / 4;
    constexpr int NT  = CG * G;        // block threads
    constexpr int NPB = 2 * G;         // nodes per block
    constexpr int RS  = STRIDE + 4;    // padded row stride (words): spreads banks, keeps 16B align
    __shared__ float xs[NPB * RS];
    const int tid = threadIdx.x;
    const int n0  = blockIdx.x * NPB;

    // stage X rows (float4, coalesced) into padded LDS rows
    constexpr int C4 = STRIDE / 4;     // float4s per row
    const float4* Xv = (const float4*)(X + (size_t)n0 * STRIDE);
    for (int i = tid; i < NPB * C4; i += NT) {
        const int nl = i / C4, r = i - nl * C4;
        float4 v = make_float4(0.f, 0.f, 0.f, 0.f);
        if (n0 + nl < NN) v = Xv[nl * C4 + r];
        *(float4*)(xs + nl * RS + r * 4) = v;
    }
    __syncthreads();

    const int cg = tid % CG;
    const int g  = tid / CG;
    const float* x0 = xs + (2 * g) * RS;
    const float* x1 = xs + (2 * g + 1) * RS;
    const float4* Wv = (const float4*)W;

    float4 a0 = make_float4(0.f, 0.f, 0.f, 0.f);
    float4 a1 = make_float4(0.f, 0.f, 0.f, 0.f);
#pragma unroll 8
    for (int k = 0; k < K; ++k) {
        const float4 w = Wv[k * CG + cg];
        const float v0 = x0[k], v1 = x1[k];
        a0.x = fmaf(v0, w.x, a0.x); a0.y = fmaf(v0, w.y, a0.y);
        a0.z = fmaf(v0, w.z, a0.z); a0.w = fmaf(v0, w.w, a0.w);
        a1.x = fmaf(v1, w.x, a1.x); a1.y = fmaf(v1, w.y, a1.y);
        a1.z = fmaf(v1, w.z, a1.z); a1.w = fmaf(v1, w.w, a1.w);
    }

    const int node0 = n0 + 2 * g, node1 = node0 + 1;
    float4 b4 = make_float4(0.f, 0.f, 0.f, 0.f);
    if (MODE != 1) b4 = ((const float4*)bias)[cg];
#pragma unroll
    for (int h = 0; h < 2; ++h) {
        const int node = h ? node1 : node0;
        if (node >= NN) continue;
        float4 a = h ? a1 : a0;
        float4 r;
        if (MODE == 0) {
            r.x = a.x + b4.x; r.y = a.y + b4.y; r.z = a.z + b4.z; r.w = a.w + b4.w;
        } else if (MODE == 1) {
            const float d = dis[node];
            r.x = a.x * d; r.y = a.y * d; r.z = a.z * d; r.w = a.w * d;
        } else {
            const float d = dis[node];
            r.x = fmaxf(a.x + b4.x, 0.f) * d; r.y = fmaxf(a.y + b4.y, 0.f) * d;
            r.z = fmaxf(a.z + b4.z, 0.f) * d; r.w = fmaxf(a.w + b4.w, 0.f) * d;
        }
        ((float4*)(out + (size_t)node * FOUT))[cg] = r;
    }
}

extern "C" void kernel_launch(void* const* d_in, const int* in_sizes, int n_in,
                              void* d_out, int out_size, void* d_ws, size_t ws_size,
                              hipStream_t stream) {
    const float* x  = (const float*)d_in[0];
    const int*   ei = (const int*)d_in[1];           // int32 (harness converts)
    const float* W1 = (const float*)d_in[2]; const float* b1 = (const float*)d_in[3];
    const float* W2 = (const float*)d_in[4]; const float* b2 = (const float*)d_in[5];
    const float* W3 = (const float*)d_in[6]; const float* b3 = (const float*)d_in[7];
    const float* W4 = (const float*)d_in[8]; const float* b4 = (const float*)d_in[9];
    float* out = (float*)d_out;

    const int E = in_sizes[1] / 2;          // 800000
    const int* row = ei;
    const int* col = ei + E;

    // Workspace (4B elems): cnt i32[50048] | dis f32[50048] | ell i32[CAP*NN]
    //                      | B0 f32[N*128] | B1 f32[N*128]    (~64.4 MB)
    int*   cnt = (int*)d_ws;
    float* dis = (float*)(cnt + 50048);
    int*   ell = (int*)(dis + 50048);
    float* B0  = (float*)(ell + (size_t)CAP * NN);
    float* B1  = B0 + (size_t)NN * 128;

    // --- build ELL + dis ---
    hipMemsetAsync(cnt, 0, 50048 * sizeof(int), stream);
    place_ell_kernel<<<(E + 255) / 256, 256, 0, stream>>>(row, col, cnt, ell, E);
    dis_kernel<<<(NN + 255) / 256, 256, 0, stream>>>(cnt, dis, NN);
    xpad_kernel<<<(NN * 32 + 255) / 256, 256, 0, stream>>>(x, dis, B0);

    // --- layer 1 (agg-first): agg32(B0->B1); gemm 29->96 relu(+b)*dis (B1->B0)
    aggregate_kernel<32, false><<<(NN * 8 + 255) / 256, 256, 0, stream>>>(B0, cnt, ell, dis, nullptr, B1);
    gemm_rb_kernel<29, 32, 96, 8, 2><<<(NN + 15) / 16, 192, 0, stream>>>(B1, W1, b1, dis, B0);

    // --- layer 2 (agg-first): agg96(B0->B1); gemm 96->128 +b (B1->B0)
    aggregate_kernel<96, false><<<(NN * 24 + 255) / 256, 256, 0, stream>>>(B0, cnt, ell, dis, nullptr, B1);
    gemm_rb_kernel<96, 96, 128, 8, 0><<<(NN + 15) / 16, 256, 0, stream>>>(B1, W2, b2, dis, B0);

    // --- layer 3 (gemm-first): gemm 128->64 *dis (B0->B1); agg64 +b3 (B1->B0)
    gemm_rb_kernel<128, 128, 64, 16, 1><<<(NN + 31) / 32, 256, 0, stream>>>(B0, W3, nullptr, dis, B1);
    aggregate_kernel<64, true><<<(NN * 16 + 255) / 256, 256, 0, stream>>>(B1, cnt, ell, dis, b3, B0);

    // --- layer 4 (gemm-first): gemm 64->32 *dis (B0->B1); agg32 +b4 (B1->out)
    gemm_rb_kernel<64, 64, 32, 32, 1><<<(NN + 63) / 64, 256, 0, stream>>>(B0, W4, nullptr, dis, B1);
    aggregate_kernel<32, true><<<(NN * 8 + 255) / 256, 256, 0, stream>>>(B1, cnt, ell, dis, b4, out);
}

// Round 7
// 260.681 us; speedup vs baseline: 7.5694x; 1.4078x over previous
//
#include <hip/hip_runtime.h>

// GCN 4-layer: 29->96->128->64->32, N=50000, E=800000 (+self loops).
// Round 7: layers 2-4 are linear => collapse:
//   out = A^3 (h1 W2W3W4) + c2 (x) (b2 W3W4) + c1 (x) (b3 W4) + 1 (x) b4
// where A = D^-1/2 (Adj+I) D^-1/2, c1 = A.1, c2 = A^2.1 (width-1 aggs).
// Aggregation: 1x agg32 (layer1 pre-agg) + 3x chained agg32; gather volume
// 128 floats/edge (was 224), gathered arrays 6.4 MB (L2-friendly).
// ELL is row-major (ell[n*64+k]) so indices load as int4 -> 4 independent
// gathers in flight (round-6 agg was latency-bound: VALUBusy 6.8%).
// Sentinel index NN -> maintained zero row (buffers have NN+1 rows).
// NOTE: harness delivers integer inputs as int32.

constexpr int NN  = 50000;
constexpr int CAP = 64;   // max in-degree; Poisson(16) over 50K nodes => P(>=64) ~ 0

// Fused degree-count + ELL placement (row-major). cnt must be zeroed first.
__global__ void place_ell_kernel(const int* __restrict__ row, const int* __restrict__ col,
                                 int* __restrict__ cnt, int* __restrict__ ell, int E) {
    int e = blockIdx.x * blockDim.x + threadIdx.x;
    if (e < E) {
        int c = col[e], r = row[e];
        if ((unsigned)c < (unsigned)NN && (unsigned)r < (unsigned)NN) {
            int pos = atomicAdd(&cnt[c], 1);
            if (pos < CAP) ell[c * CAP + pos] = r;   // guard keeps rocprof replays safe
        }
    }
}

__global__ void dis_kernel(const int* __restrict__ cnt, float* __restrict__ dis, int n) {
    int i = blockIdx.x * blockDim.x + threadIdx.x;
    if (i < n) dis[i] = rsqrtf((float)cnt[i] + 1.0f);  // +1 = self loop
}

// Pad each node's ELL list to a multiple of 4 with sentinel NN; zero the
// sentinel rows / entries used by gathers.
__global__ void prep_kernel(const int* __restrict__ cnt, int* __restrict__ ell,
                            float* __restrict__ dis, float* __restrict__ Ba,
                            float* __restrict__ Bb, float* __restrict__ c1d) {
    int i = blockIdx.x * blockDim.x + threadIdx.x;
    if (i < NN) {
        int m = cnt[i]; if (m > CAP) m = CAP;
        int mp = (m + 3) & ~3; if (mp > CAP) mp = CAP;
        for (int k = m; k < mp; ++k) ell[i * CAP + k] = NN;
    } else if (i == NN) {
        dis[NN] = 0.f; c1d[NN] = 0.f;
    }
    if (i < 32) { Ba[NN * 32 + i] = 0.f; Bb[NN * 32 + i] = 0.f; }
}

// x (N x 29) -> xp (N x 32), pre-scaled by dis[n], cols 29..31 = 0.
__global__ void xpad_kernel(const float* __restrict__ x, const float* __restrict__ dis,
                            float* __restrict__ xp) {
    int idx = blockIdx.x * blockDim.x + threadIdx.x;
    if (idx < NN * 32) {
        int n = idx >> 5, f = idx & 31;
        xp[idx] = (f < 29) ? x[n * 29 + f] * dis[n] : 0.f;
    }
}

// W34 = W3(128x64) @ W4(64x32); v1 = b3 @ W4.
__global__ void w34_kernel(const float* __restrict__ W3, const float* __restrict__ W4,
                           const float* __restrict__ b3, float* __restrict__ W34,
                           float* __restrict__ v1) {
    int idx = blockIdx.x * blockDim.x + threadIdx.x;
    if (idx < 128 * 32) {
        int r = idx >> 5, j = idx & 31;
        float a = 0.f;
        for (int k = 0; k < 64; ++k) a = fmaf(W3[r * 64 + k], W4[k * 32 + j], a);
        W34[idx] = a;
    }
    if (idx < 32) {
        float a = 0.f;
        for (int k = 0; k < 64; ++k) a = fmaf(b3[k], W4[k * 32 + idx], a);
        v1[idx] = a;
    }
}

// W234 = W2(96x128) @ W34(128x32); v2 = b2 @ W34.
__global__ void w234_kernel(const float* __restrict__ W2, const float* __restrict__ W34,
                            const float* __restrict__ b2, float* __restrict__ W234,
                            float* __restrict__ v2) {
    int idx = blockIdx.x * blockDim.x + threadIdx.x;
    if (idx < 96 * 32) {
        int r = idx >> 5, j = idx & 31;
        float a = 0.f;
        for (int k = 0; k < 128; ++k) a = fmaf(W2[r * 128 + k], W34[k * 32 + j], a);
        W234[idx] = a;
    }
    if (idx < 32) {
        float a = 0.f;
        for (int k = 0; k < 128; ++k) a = fmaf(b2[k], W34[k * 32 + idx], a);
        v2[idx] = a;
    }
}

// Width-1 aggregation: out = dis[n]*(in[n]+sum in[src]); outd = out*dis (chain).
template<bool OUTD>
__global__ void agg1_kernel(const float* __restrict__ in, const int* __restrict__ cnt,
                            const int* __restrict__ ell, const float* __restrict__ dis,
                            float* __restrict__ out, float* __restrict__ outd) {
    int n = blockIdx.x * blockDim.x + threadIdx.x;
    if (n >= NN) return;
    float acc = in[n];
    int m = cnt[n]; if (m > CAP) m = CAP;
    const int m4 = (m + 3) >> 2;
    const int4* ip = (const int4*)(ell + n * CAP);
    for (int t = 0; t < m4; ++t) {
        int4 s = ip[t];
        acc += in[s.x] + in[s.y] + in[s.z] + in[s.w];
    }
    float r = dis[n] * acc;
    out[n] = r;
    if (OUTD) outd[n] = r * dis[n];
}

// Width-32 aggregation over row-major ELL, int4 index batching.
// Thread = (node, float4 chunk c of 8). acc = hs[n] (self) + sum hs[src].
// MODE: 0 plain:  out = dis*acc
//       1 chain:  out = dis*dis*acc           (pre-scaled for next agg)
//       2 final:  out = dis*acc + c1*v1 + c2*v2 + b4
template<int MODE>
__global__ void agg32_kernel(const float* __restrict__ hs, const int* __restrict__ cnt,
                             const int* __restrict__ ell, const float* __restrict__ dis,
                             const float* __restrict__ c1, const float* __restrict__ c2,
                             const float* __restrict__ v1, const float* __restrict__ v2,
                             const float* __restrict__ b4, float* __restrict__ out) {
    const int idx = blockIdx.x * blockDim.x + threadIdx.x;
    if (idx >= NN * 8) return;
    const int n = idx >> 3, c = idx & 7;
    const float4* hp = (const float4*)hs;
    float4 acc = hp[(size_t)n * 8 + c];          // self-loop term
    int m = cnt[n]; if (m > CAP) m = CAP;
    const int m4 = (m + 3) >> 2;
    const int4* ip = (const int4*)(ell + n * CAP);
    for (int t = 0; t < m4; ++t) {
        const int4 s = ip[t];                    // 4 independent gathers in flight
        const float4 g0 = hp[(size_t)s.x * 8 + c];
        const float4 g1 = hp[(size_t)s.y * 8 + c];
        const float4 g2 = hp[(size_t)s.z * 8 + c];
        const float4 g3 = hp[(size_t)s.w * 8 + c];
        acc.x += (g0.x + g1.x) + (g2.x + g3.x);
        acc.y += (g0.y + g1.y) + (g2.y + g3.y);
        acc.z += (g0.z + g1.z) + (g2.z + g3.z);
        acc.w += (g0.w + g1.w) + (g2.w + g3.w);
    }
    const float d = dis[n];
    float4 r;
    if (MODE == 0) {
        r.x = acc.x * d; r.y = acc.y * d; r.z = acc.z * d; r.w = acc.w * d;
    } else if (MODE == 1) {
        const float d2 = d * d;
        r.x = acc.x * d2; r.y = acc.y * d2; r.z = acc.z * d2; r.w = acc.w * d2;
    } else {
        const float a1 = c1[n], a2 = c2[n];
        const float4 w1 = ((const float4*)v1)[c];
        const float4 w2 = ((const float4*)v2)[c];
        const float4 bb = ((const float4*)b4)[c];
        r.x = fmaf(acc.x, d, fmaf(a1, w1.x, fmaf(a2, w2.x, bb.x)));
        r.y = fmaf(acc.y, d, fmaf(a1, w1.y, fmaf(a2, w2.y, bb.y)));
        r.z = fmaf(acc.z, d, fmaf(a1, w1.z, fmaf(a2, w2.z, bb.z)));
        r.w = fmaf(acc.w, d, fmaf(a1, w1.w, fmaf(a2, w2.w, bb.w)));
    }
    ((float4*)out)[idx] = r;
}

// Register-blocked GEMM (round 6): thread = (4 cols, node-pair).
// MODE: 0 = acc + b ; 1 = acc * dis ; 2 = relu(acc + b) * dis ; 3 = acc
template<int K, int STRIDE, int FOUT, int G, int MODE>
__global__ void gemm_rb_kernel(const float* __restrict__ X, const float* __restrict__ W,
                               const float* __restrict__ bias, const float* __restrict__ dis,
                               float* __restrict__ out) {
    constexpr int CG  = FOUT / 4;
    constexpr int NT  = CG * G;
    constexpr int NPB = 2 * G;
    constexpr int RS  = STRIDE + 4;
    __shared__ float xs[NPB * RS];
    const int tid = threadIdx.x;
    const int n0  = blockIdx.x * NPB;

    constexpr int C4 = STRIDE / 4;
    const float4* Xv = (const float4*)(X + (size_t)n0 * STRIDE);
    for (int i = tid; i < NPB * C4; i += NT) {
        const int nl = i / C4, r = i - nl * C4;
        float4 v = make_float4(0.f, 0.f, 0.f, 0.f);
        if (n0 + nl < NN) v = Xv[nl * C4 + r];
        *(float4*)(xs + nl * RS + r * 4) = v;
    }
    __syncthreads();

    const int cg = tid % CG;
    const int g  = tid / CG;
    const float* x0 = xs + (2 * g) * RS;
    const float* x1 = xs + (2 * g + 1) * RS;
    const float4* Wv = (const float4*)W;

    float4 a0 = make_float4(0.f, 0.f, 0.f, 0.f);
    float4 a1 = make_float4(0.f, 0.f, 0.f, 0.f);
#pragma unroll 8
    for (int k = 0; k < K; ++k) {
        const float4 w = Wv[k * CG + cg];
        const float v0 = x0[k], v1 = x1[k];
        a0.x = fmaf(v0, w.x, a0.x); a0.y = fmaf(v0, w.y, a0.y);
        a0.z = fmaf(v0, w.z, a0.z); a0.w = fmaf(v0, w.w, a0.w);
        a1.x = fmaf(v1, w.x, a1.x); a1.y = fmaf(v1, w.y, a1.y);
        a1.z = fmaf(v1, w.z, a1.z); a1.w = fmaf(v1, w.w, a1.w);
    }

    const int node0 = n0 + 2 * g, node1 = node0 + 1;
    float4 b4 = make_float4(0.f, 0.f, 0.f, 0.f);
    if (MODE == 0 || MODE == 2) b4 = ((const float4*)bias)[cg];
#pragma unroll
    for (int h = 0; h < 2; ++h) {
        const int node = h ? node1 : node0;
        if (node >= NN) continue;
        float4 a = h ? a1 : a0;
        float4 r;
        if (MODE == 0) {
            r.x = a.x + b4.x; r.y = a.y + b4.y; r.z = a.z + b4.z; r.w = a.w + b4.w;
        } else if (MODE == 1) {
            const float d = dis[node];
            r.x = a.x * d; r.y = a.y * d; r.z = a.z * d; r.w = a.w * d;
        } else if (MODE == 2) {
            const float d = dis[node];
            r.x = fmaxf(a.x + b4.x, 0.f) * d; r.y = fmaxf(a.y + b4.y, 0.f) * d;
            r.z = fmaxf(a.z + b4.z, 0.f) * d; r.w = fmaxf(a.w + b4.w, 0.f) * d;
        } else {
            r = a;
        }
        ((float4*)(out + (size_t)node * FOUT))[cg] = r;
    }
}

extern "C" void kernel_launch(void* const* d_in, const int* in_sizes, int n_in,
                              void* d_out, int out_size, void* d_ws, size_t ws_size,
                              hipStream_t stream) {
    const float* x  = (const float*)d_in[0];
    const int*   ei = (const int*)d_in[1];           // int32 (harness converts)
    const float* W1 = (const float*)d_in[2]; const float* b1 = (const float*)d_in[3];
    const float* W2 = (const float*)d_in[4]; const float* b2 = (const float*)d_in[5];
    const float* W3 = (const float*)d_in[6]; const float* b3 = (const float*)d_in[7];
    const float* W4 = (const float*)d_in[8]; const float* b4 = (const float*)d_in[9];
    float* out = (float*)d_out;

    const int E = in_sizes[1] / 2;          // 800000
    const int* row = ei;
    const int* col = ei + E;

    // Workspace (4B elems, 16B-aligned sections):
    int*   cnt  = (int*)d_ws;                       // 50048
    float* dis  = (float*)(cnt + 50048);            // 50056 (uses [NN])
    int*   ell  = (int*)(dis + 50056);              // NN*CAP = 3.2M
    float* c1   = (float*)(ell + (size_t)NN * CAP); // 50056
    float* c1d  = c1 + 50056;                       // 50056 (uses [NN])
    float* c2   = c1d + 50056;                      // 50056
    float* W34  = c2 + 50056;                       // 4096
    float* W234 = W34 + 4096;                       // 3072
    float* v1   = W234 + 3072;                      // 32
    float* v2   = v1 + 32;                          // 32
    float* Ba   = v2 + 32;                          // (NN+1)*32 -> 1600064
    float* Bb   = Ba + 1600064;                     // 1600064
    float* Bh   = Bb + 1600064;                     // NN*96
    // total ~46 MB

    // --- build ELL + dis + pads ---
    hipMemsetAsync(cnt, 0, 50048 * sizeof(int), stream);
    place_ell_kernel<<<(E + 255) / 256, 256, 0, stream>>>(row, col, cnt, ell, E);
    dis_kernel<<<(NN + 255) / 256, 256, 0, stream>>>(cnt, dis, NN);
    prep_kernel<<<(NN + 64 + 255) / 256, 256, 0, stream>>>(cnt, ell, dis, Ba, Bb, c1d);
    xpad_kernel<<<(NN * 32 + 255) / 256, 256, 0, stream>>>(x, dis, Ba);

    // --- collapsed weights + bias vectors ---
    w34_kernel<<<16, 256, 0, stream>>>(W3, W4, b3, W34, v1);
    w234_kernel<<<12, 256, 0, stream>>>(W2, W34, b2, W234, v2);

    // --- c1 = A.1, c2 = A^2.1 ---
    agg1_kernel<true><<<(NN + 255) / 256, 256, 0, stream>>>(dis, cnt, ell, dis, c1, c1d);
    agg1_kernel<false><<<(NN + 255) / 256, 256, 0, stream>>>(c1d, cnt, ell, dis, c2, nullptr);

    const int AGB = (NN * 8 + 255) / 256;

    // --- layer 1: agg32 plain (Ba->Bb); gemm 29->96 relu(+b1)*dis (Bb->Bh) ---
    agg32_kernel<0><<<AGB, 256, 0, stream>>>(Ba, cnt, ell, dis, nullptr, nullptr, nullptr, nullptr, nullptr, Bb);
    gemm_rb_kernel<29, 32, 96, 8, 2><<<(NN + 15) / 16, 192, 0, stream>>>(Bb, W1, b1, dis, Bh);

    // --- g = h1d @ W234 (96->32, raw; rows already carry dis) (Bh->Ba) ---
    gemm_rb_kernel<96, 96, 32, 32, 3><<<(NN + 63) / 64, 256, 0, stream>>>(Bh, W234, nullptr, nullptr, Ba);

    // --- A^3 chain: 2x chained agg32 + final with rank-1 bias fixups ---
    agg32_kernel<1><<<AGB, 256, 0, stream>>>(Ba, cnt, ell, dis, nullptr, nullptr, nullptr, nullptr, nullptr, Bb);
    agg32_kernel<1><<<AGB, 256, 0, stream>>>(Bb, cnt, ell, dis, nullptr, nullptr, nullptr, nullptr, nullptr, Ba);
    agg32_kernel<2><<<AGB, 256, 0, stream>>>(Ba, cnt, ell, dis, c1, c2, v1, v2, b4, out);
}